// Round 1
// baseline (264.941 us; speedup 1.0000x reference)
//
#include <hip/hip_runtime.h>
#include <hip/hip_bf16.h>

#define OUT_DIM 256
#define COND_DIM 512
#define NODE_DIM 256
#define ROWS 8
#define SCAN_ITEMS 1024
#define LN_EPS 1e-5f

// ---------------- FiLM params: gb = cond @ Wc + bc; gamma=gb[:,:256]+1, beta=gb[:,256:]
__global__ void film_kernel(const float* __restrict__ cond, const float* __restrict__ Wc,
                            const float* __restrict__ bc, float* __restrict__ gamma,
                            float* __restrict__ beta) {
    int b = blockIdx.x;
    int half = blockIdx.y;                    // 0 -> gamma, 1 -> beta
    int o = half * 256 + threadIdx.x;         // column in [0,512)
    __shared__ float c[COND_DIM];
    for (int k = threadIdx.x; k < COND_DIM; k += 256) c[k] = cond[b * COND_DIM + k];
    __syncthreads();
    float acc = bc[o];
    for (int k = 0; k < COND_DIM; k += 4) {
        float4 cv = *(const float4*)&c[k];
        acc += cv.x * Wc[(k + 0) * 512 + o];
        acc += cv.y * Wc[(k + 1) * 512 + o];
        acc += cv.z * Wc[(k + 2) * 512 + o];
        acc += cv.w * Wc[(k + 3) * 512 + o];
    }
    if (half == 0) gamma[b * 256 + threadIdx.x] = acc + 1.0f;
    else           beta[b * 256 + threadIdx.x] = acc;
}

// ---------------- x = relu(LN(node_feats @ Wl) * gamma[bid] + beta[bid])
__global__ void node_kernel(const float* __restrict__ nf, const float* __restrict__ Wl,
                            const int* __restrict__ batch_ids, const float* __restrict__ gamma,
                            const float* __restrict__ beta, float* __restrict__ xout, int N) {
    __shared__ float tile[ROWS][NODE_DIM];    // 8 KB; reused to hold x after the GEMM
    __shared__ float mu_s[ROWS], rs_s[ROWS];
    __shared__ int bid_s[ROWS];
    int n0 = blockIdx.x * ROWS;
    int t = threadIdx.x;

    #pragma unroll
    for (int r = 0; r < ROWS; ++r) tile[r][t] = nf[(n0 + r) * NODE_DIM + t];
    if (t < ROWS) bid_s[t] = batch_ids[n0 + t];
    __syncthreads();

    float acc[ROWS];
    #pragma unroll
    for (int r = 0; r < ROWS; ++r) acc[r] = 0.f;

    for (int k = 0; k < NODE_DIM; k += 4) {
        float w0 = Wl[(k + 0) * OUT_DIM + t];
        float w1 = Wl[(k + 1) * OUT_DIM + t];
        float w2 = Wl[(k + 2) * OUT_DIM + t];
        float w3 = Wl[(k + 3) * OUT_DIM + t];
        #pragma unroll
        for (int r = 0; r < ROWS; ++r) {
            float4 v = *(const float4*)&tile[r][k];   // broadcast read, conflict-free
            acc[r] += v.x * w0 + v.y * w1 + v.z * w2 + v.w * w3;
        }
    }
    __syncthreads();
    #pragma unroll
    for (int r = 0; r < ROWS; ++r) tile[r][t] = acc[r];
    __syncthreads();

    // LN stats: wave w reduces rows 2w, 2w+1 (64 lanes x float4 = 256 values)
    int wave = t >> 6, lane = t & 63;
    #pragma unroll
    for (int rr = 0; rr < 2; ++rr) {
        int r = wave * 2 + rr;
        float4 v = *(const float4*)&tile[r][lane * 4];
        float s = v.x + v.y + v.z + v.w;
        float s2 = v.x * v.x + v.y * v.y + v.z * v.z + v.w * v.w;
        #pragma unroll
        for (int off = 32; off; off >>= 1) {
            s += __shfl_xor(s, off);
            s2 += __shfl_xor(s2, off);
        }
        if (lane == 0) {
            float mu = s * (1.f / OUT_DIM);
            float var = s2 * (1.f / OUT_DIM) - mu * mu;
            mu_s[r] = mu;
            rs_s[r] = rsqrtf(var + LN_EPS);
        }
    }
    __syncthreads();

    #pragma unroll
    for (int r = 0; r < ROWS; ++r) {
        int b = bid_s[r];
        float v = (tile[r][t] - mu_s[r]) * rs_s[r];
        v = v * gamma[b * OUT_DIM + t] + beta[b * OUT_DIM + t];
        xout[(n0 + r) * OUT_DIM + t] = fmaxf(v, 0.f);
    }
}

// ---------------- CSR build: count -> scan (3 kernels) -> fill
__global__ void count_kernel(const int* __restrict__ ni, int* __restrict__ counts, int E) {
    int e = blockIdx.x * blockDim.x + threadIdx.x;
    if (e < E) atomicAdd(&counts[ni[e]], 1);
}

__global__ void scan1_kernel(const int* __restrict__ counts, int* __restrict__ row_start,
                             int* __restrict__ blocksum, int N) {
    __shared__ int ssum[256];
    int base = blockIdx.x * SCAN_ITEMS + threadIdx.x * 4;
    int v[4];
    #pragma unroll
    for (int i = 0; i < 4; ++i) v[i] = (base + i < N) ? counts[base + i] : 0;
    int tsum = v[0] + v[1] + v[2] + v[3];
    ssum[threadIdx.x] = tsum;
    __syncthreads();
    for (int off = 1; off < 256; off <<= 1) {
        int x = (threadIdx.x >= (unsigned)off) ? ssum[threadIdx.x - off] : 0;
        __syncthreads();
        ssum[threadIdx.x] += x;
        __syncthreads();
    }
    int run = ssum[threadIdx.x] - tsum;   // exclusive prefix of this thread
    #pragma unroll
    for (int i = 0; i < 4; ++i) {
        if (base + i < N) row_start[base + i] = run;
        run += v[i];
    }
    if (threadIdx.x == 255) blocksum[blockIdx.x] = ssum[255];
}

__global__ void scan2_kernel(const int* __restrict__ blocksum, int* __restrict__ blockoff,
                             int* __restrict__ row_start, int nb, int N) {
    if (threadIdx.x == 0 && blockIdx.x == 0) {
        int run = 0;
        for (int b = 0; b < nb; ++b) { blockoff[b] = run; run += blocksum[b]; }
        row_start[N] = run;   // == E
    }
}

__global__ void scan3_kernel(int* __restrict__ row_start, const int* __restrict__ blockoff, int N) {
    int base = blockIdx.x * SCAN_ITEMS + threadIdx.x * 4;
    int off = blockoff[blockIdx.x];
    #pragma unroll
    for (int i = 0; i < 4; ++i)
        if (base + i < N) row_start[base + i] += off;
}

__global__ void fill_kernel(const int* __restrict__ nj, const int* __restrict__ ni,
                            const float* __restrict__ ew, const float* __restrict__ ep,
                            const int* __restrict__ row_start, int* __restrict__ cursor,
                            int* __restrict__ ej, float* __restrict__ ewt, int E) {
    int e = blockIdx.x * blockDim.x + threadIdx.x;
    if (e < E) {
        int i = ni[e];
        int pos = row_start[i] + atomicAdd(&cursor[i], 1);
        ej[pos] = nj[e];
        ewt[pos] = ew[e] * ep[e];
    }
}

// ---------------- aggregation: one wave per destination node, no atomics
__global__ void agg_kernel(const float* __restrict__ x, const int* __restrict__ ej,
                           const float* __restrict__ ewt, const int* __restrict__ row_start,
                           float* __restrict__ out, int N) {
    int node = blockIdx.x * 4 + (threadIdx.x >> 6);
    int lane = threadIdx.x & 63;
    if (node >= N) return;
    int s = row_start[node], e = row_start[node + 1];
    float4 acc = {0.f, 0.f, 0.f, 0.f};
    for (int p = s; p < e; ++p) {
        int j = ej[p];            // wave-uniform
        float w = ewt[p];         // wave-uniform
        float4 xv = *(const float4*)&x[j * OUT_DIM + lane * 4];
        acc.x += xv.x * w; acc.y += xv.y * w; acc.z += xv.z * w; acc.w += xv.w * w;
    }
    float4 o;
    o.x = fmaxf(acc.x, 0.f); o.y = fmaxf(acc.y, 0.f);
    o.z = fmaxf(acc.z, 0.f); o.w = fmaxf(acc.w, 0.f);
    *(float4*)&out[node * OUT_DIM + lane * 4] = o;
}

extern "C" void kernel_launch(void* const* d_in, const int* in_sizes, int n_in,
                              void* d_out, int out_size, void* d_ws, size_t ws_size,
                              hipStream_t stream) {
    const float* node_feats = (const float*)d_in[0];
    const float* cond_feats = (const float*)d_in[1];
    const int*   batch_ids  = (const int*)d_in[2];
    const int*   node_j     = (const int*)d_in[3];
    const int*   node_i     = (const int*)d_in[4];
    const float* edge_w     = (const float*)d_in[5];
    const float* edge_p     = (const float*)d_in[6];
    const float* Wc         = (const float*)d_in[7];
    const float* bc         = (const float*)d_in[8];
    const float* Wl         = (const float*)d_in[9];
    float* out = (float*)d_out;

    const int N = in_sizes[2];
    const int E = in_sizes[3];
    const int B = in_sizes[1] / COND_DIM;

    // workspace layout (16B-aligned chunks)
    char* ws = (char*)d_ws;
    float* gamma     = (float*)ws;                 ws += (size_t)B * OUT_DIM * 4;
    float* beta      = (float*)ws;                 ws += (size_t)B * OUT_DIM * 4;
    float* x         = (float*)ws;                 ws += (size_t)N * OUT_DIM * 4;
    int*   counts    = (int*)ws;                   ws += (size_t)N * 4;
    int*   cursor    = (int*)ws;                   ws += (size_t)N * 4;
    int*   row_start = (int*)ws;                   ws += (size_t)(N + 4) * 4;
    int*   blocksum  = (int*)ws;                   ws += 256 * 4;
    int*   blockoff  = (int*)ws;                   ws += 256 * 4;
    int*   ej        = (int*)ws;                   ws += (size_t)E * 4;
    float* ewt       = (float*)ws;                 ws += (size_t)E * 4;

    // zero counts + cursor (adjacent -> one memset)
    hipMemsetAsync(counts, 0, (size_t)N * 2 * 4, stream);

    film_kernel<<<dim3(B, 2), 256, 0, stream>>>(cond_feats, Wc, bc, gamma, beta);
    node_kernel<<<(N + ROWS - 1) / ROWS, 256, 0, stream>>>(node_feats, Wl, batch_ids,
                                                           gamma, beta, x, N);
    count_kernel<<<(E + 255) / 256, 256, 0, stream>>>(node_i, counts, E);
    int nb = (N + SCAN_ITEMS - 1) / SCAN_ITEMS;
    scan1_kernel<<<nb, 256, 0, stream>>>(counts, row_start, blocksum, N);
    scan2_kernel<<<1, 64, 0, stream>>>(blocksum, blockoff, row_start, nb, N);
    scan3_kernel<<<nb, 256, 0, stream>>>(row_start, blockoff, N);
    fill_kernel<<<(E + 255) / 256, 256, 0, stream>>>(node_j, node_i, edge_w, edge_p,
                                                     row_start, cursor, ej, ewt, E);
    agg_kernel<<<(N + 3) / 4, 256, 0, stream>>>(x, ej, ewt, row_start, out, N);
}

// Round 2
// 233.321 us; speedup vs baseline: 1.1355x; 1.1355x over previous
//
#include <hip/hip_runtime.h>
#include <hip/hip_bf16.h>

#define OUT_DIM 256
#define COND_DIM 512
#define NODE_DIM 256
#define TM 64
#define LDA 264          // 256 + 8 bf16 pad: row stride 528B, breaks bank aliasing
#define SCAN_ITEMS 1024
#define LN_EPS 1e-5f

typedef __attribute__((ext_vector_type(8))) short bf16x8;
typedef __attribute__((ext_vector_type(4))) float f32x4;

__device__ inline unsigned short f2bf(float f) {
    unsigned u = __float_as_uint(f);
    u += 0x7fffu + ((u >> 16) & 1u);           // RNE
    return (unsigned short)(u >> 16);
}

// ---------------- Wl [256x256] fp32 row-major -> WlT bf16 column-major (WlT[n*256+k])
__global__ void convb_kernel(const float* __restrict__ Wl, unsigned short* __restrict__ WlT) {
    __shared__ float tile[64][65];
    int bx = blockIdx.x & 3, by = blockIdx.x >> 2;    // 4x4 tiles of 64x64
    int tr = threadIdx.x >> 6, tc = threadIdx.x & 63;
    #pragma unroll
    for (int rr = 0; rr < 64; rr += 4)
        tile[rr + tr][tc] = Wl[(by * 64 + rr + tr) * OUT_DIM + bx * 64 + tc];
    __syncthreads();
    #pragma unroll
    for (int rr = 0; rr < 64; rr += 4) {
        int n = bx * 64 + rr + tr;
        int k = by * 64 + tc;
        WlT[n * NODE_DIM + k] = f2bf(tile[tc][rr + tr]);
    }
}

// ---------------- FiLM params
__global__ void film_kernel(const float* __restrict__ cond, const float* __restrict__ Wc,
                            const float* __restrict__ bc, float* __restrict__ gamma,
                            float* __restrict__ beta) {
    int b = blockIdx.x;
    int half = blockIdx.y;
    int o = half * 256 + threadIdx.x;
    __shared__ float c[COND_DIM];
    for (int k = threadIdx.x; k < COND_DIM; k += 256) c[k] = cond[b * COND_DIM + k];
    __syncthreads();
    float acc = bc[o];
    for (int k = 0; k < COND_DIM; k += 4) {
        float4 cv = *(const float4*)&c[k];
        acc += cv.x * Wc[(k + 0) * 512 + o];
        acc += cv.y * Wc[(k + 1) * 512 + o];
        acc += cv.z * Wc[(k + 2) * 512 + o];
        acc += cv.w * Wc[(k + 3) * 512 + o];
    }
    if (half == 0) gamma[b * 256 + threadIdx.x] = acc + 1.0f;
    else           beta[b * 256 + threadIdx.x] = acc;
}

// ---------------- x = relu(LN(nf @ Wl) * gamma[bid] + beta[bid]) via bf16 MFMA
// block = 256 threads (4 waves), computes 64 rows x 256 cols
__global__ __launch_bounds__(256) void node_mfma_kernel(
        const float* __restrict__ nf, const unsigned short* __restrict__ WlT,
        const int* __restrict__ batch_ids, const float* __restrict__ gamma,
        const float* __restrict__ beta, float* __restrict__ xout, int N) {
    __shared__ unsigned short Atile[TM * LDA];     // bf16 A tile, padded
    __shared__ int bid_s[TM];
    int t = threadIdx.x;
    int n0 = blockIdx.x * TM;

    // stage A: 64 rows x 256 fp32 -> bf16 LDS (coalesced float4 loads)
    #pragma unroll
    for (int it = 0; it < 16; ++it) {
        int idx = t + it * 256;                    // 0..4095
        int r = idx >> 6;                          // 64 float4-chunks per row
        int c4 = idx & 63;
        int row = n0 + r;
        float4 v;
        if (row < N) v = *(const float4*)&nf[(size_t)row * NODE_DIM + c4 * 4];
        else         v = make_float4(0.f, 0.f, 0.f, 0.f);
        unsigned short b0 = f2bf(v.x), b1 = f2bf(v.y), b2 = f2bf(v.z), b3 = f2bf(v.w);
        unsigned* dst = (unsigned*)&Atile[r * LDA + c4 * 4];
        dst[0] = (unsigned)b0 | ((unsigned)b1 << 16);
        dst[1] = (unsigned)b2 | ((unsigned)b3 << 16);
    }
    if (t < TM) bid_s[t] = (n0 + t < N) ? batch_ids[n0 + t] : 0;
    __syncthreads();

    int wave = t >> 6;
    int lane = t & 63;
    int l = lane & 15;
    int quad = lane >> 4;

    f32x4 acc[16];
    #pragma unroll
    for (int ct = 0; ct < 16; ++ct) acc[ct] = (f32x4){0.f, 0.f, 0.f, 0.f};

    const unsigned short* Abase = &Atile[(wave * 16 + l) * LDA + quad * 8];
    const unsigned short* Bbase = &WlT[l * NODE_DIM + quad * 8];

    #pragma unroll
    for (int ks = 0; ks < 8; ++ks) {
        bf16x8 a = *(const bf16x8*)(Abase + ks * 32);
        #pragma unroll
        for (int ct = 0; ct < 16; ++ct) {
            bf16x8 b = *(const bf16x8*)(Bbase + ct * 16 * NODE_DIM + ks * 32);
            acc[ct] = __builtin_amdgcn_mfma_f32_16x16x32_bf16(a, b, acc[ct], 0, 0, 0);
        }
    }

    // epilogue: LN (per-row over 256 cols) + FiLM + relu + store
    // C/D layout: col = ct*16 + l, row(local in wave) = quad*4 + reg
    #pragma unroll
    for (int reg = 0; reg < 4; ++reg) {
        float s = 0.f, s2 = 0.f;
        #pragma unroll
        for (int ct = 0; ct < 16; ++ct) {
            float v = acc[ct][reg];
            s += v; s2 += v * v;
        }
        #pragma unroll
        for (int off = 1; off <= 8; off <<= 1) {
            s += __shfl_xor(s, off);
            s2 += __shfl_xor(s2, off);
        }
        float mu = s * (1.f / OUT_DIM);
        float var = s2 * (1.f / OUT_DIM) - mu * mu;
        float rs = rsqrtf(var + LN_EPS);
        int lrow = wave * 16 + quad * 4 + reg;
        int grow = n0 + lrow;
        int bid = bid_s[lrow];
        const float* grow_g = &gamma[bid * OUT_DIM];
        const float* grow_b = &beta[bid * OUT_DIM];
        if (grow < N) {
            float* orow = &xout[(size_t)grow * OUT_DIM];
            #pragma unroll
            for (int ct = 0; ct < 16; ++ct) {
                int col = ct * 16 + l;
                float v = (acc[ct][reg] - mu) * rs;
                v = v * grow_g[col] + grow_b[col];
                orow[col] = fmaxf(v, 0.f);
            }
        }
    }
}

// ---------------- CSR build
__global__ void count_kernel(const int* __restrict__ ni, int* __restrict__ counts, int E) {
    int e = blockIdx.x * blockDim.x + threadIdx.x;
    if (e < E) atomicAdd(&counts[ni[e]], 1);
}

__global__ void scan1_kernel(const int* __restrict__ counts, int* __restrict__ row_start,
                             int* __restrict__ blocksum, int N) {
    __shared__ int ssum[256];
    int base = blockIdx.x * SCAN_ITEMS + threadIdx.x * 4;
    int v[4];
    #pragma unroll
    for (int i = 0; i < 4; ++i) v[i] = (base + i < N) ? counts[base + i] : 0;
    int tsum = v[0] + v[1] + v[2] + v[3];
    ssum[threadIdx.x] = tsum;
    __syncthreads();
    for (int off = 1; off < 256; off <<= 1) {
        int x = (threadIdx.x >= (unsigned)off) ? ssum[threadIdx.x - off] : 0;
        __syncthreads();
        ssum[threadIdx.x] += x;
        __syncthreads();
    }
    int run = ssum[threadIdx.x] - tsum;
    #pragma unroll
    for (int i = 0; i < 4; ++i) {
        if (base + i < N) row_start[base + i] = run;
        run += v[i];
    }
    if (threadIdx.x == 255) blocksum[blockIdx.x] = ssum[255];
}

__global__ void scan2_kernel(const int* __restrict__ blocksum, int* __restrict__ blockoff,
                             int* __restrict__ row_start, int nb, int N) {
    if (threadIdx.x == 0 && blockIdx.x == 0) {
        int run = 0;
        for (int b = 0; b < nb; ++b) { blockoff[b] = run; run += blocksum[b]; }
        row_start[N] = run;
    }
}

__global__ void scan3_kernel(int* __restrict__ row_start, const int* __restrict__ blockoff, int N) {
    int base = blockIdx.x * SCAN_ITEMS + threadIdx.x * 4;
    int off = blockoff[blockIdx.x];
    #pragma unroll
    for (int i = 0; i < 4; ++i)
        if (base + i < N) row_start[base + i] += off;
}

__global__ void fill_kernel(const int* __restrict__ nj, const int* __restrict__ ni,
                            const float* __restrict__ ew, const float* __restrict__ ep,
                            const int* __restrict__ row_start, int* __restrict__ cursor,
                            int2* __restrict__ epk, int E) {
    int e = blockIdx.x * blockDim.x + threadIdx.x;
    if (e < E) {
        int i = ni[e];
        int pos = row_start[i] + atomicAdd(&cursor[i], 1);
        epk[pos] = make_int2(nj[e], __float_as_int(ew[e] * ep[e]));
    }
}

// ---------------- aggregation: one wave per destination node, no atomics
__global__ void agg_kernel(const float* __restrict__ x, const int2* __restrict__ epk,
                           const int* __restrict__ row_start, float* __restrict__ out, int N) {
    int node = blockIdx.x * 4 + (threadIdx.x >> 6);
    int lane = threadIdx.x & 63;
    if (node >= N) return;
    int s = row_start[node], e = row_start[node + 1];
    float4 acc = {0.f, 0.f, 0.f, 0.f};
    for (int p = s; p < e; ++p) {
        int2 pk = epk[p];
        int j = pk.x;
        float w = __int_as_float(pk.y);
        float4 xv = *(const float4*)&x[(size_t)j * OUT_DIM + lane * 4];
        acc.x += xv.x * w; acc.y += xv.y * w; acc.z += xv.z * w; acc.w += xv.w * w;
    }
    float4 o;
    o.x = fmaxf(acc.x, 0.f); o.y = fmaxf(acc.y, 0.f);
    o.z = fmaxf(acc.z, 0.f); o.w = fmaxf(acc.w, 0.f);
    *(float4*)&out[(size_t)node * OUT_DIM + lane * 4] = o;
}

extern "C" void kernel_launch(void* const* d_in, const int* in_sizes, int n_in,
                              void* d_out, int out_size, void* d_ws, size_t ws_size,
                              hipStream_t stream) {
    const float* node_feats = (const float*)d_in[0];
    const float* cond_feats = (const float*)d_in[1];
    const int*   batch_ids  = (const int*)d_in[2];
    const int*   node_j     = (const int*)d_in[3];
    const int*   node_i     = (const int*)d_in[4];
    const float* edge_w     = (const float*)d_in[5];
    const float* edge_p     = (const float*)d_in[6];
    const float* Wc         = (const float*)d_in[7];
    const float* bc         = (const float*)d_in[8];
    const float* Wl         = (const float*)d_in[9];
    float* out = (float*)d_out;

    const int N = in_sizes[2];
    const int E = in_sizes[3];
    const int B = in_sizes[1] / COND_DIM;

    char* ws = (char*)d_ws;
    float* gamma     = (float*)ws;  ws += (size_t)B * OUT_DIM * 4;
    float* beta      = (float*)ws;  ws += (size_t)B * OUT_DIM * 4;
    float* x         = (float*)ws;  ws += (size_t)N * OUT_DIM * 4;
    unsigned short* WlT = (unsigned short*)ws;  ws += (size_t)NODE_DIM * OUT_DIM * 2;
    int*   counts    = (int*)ws;    ws += (size_t)N * 4;
    int*   cursor    = (int*)ws;    ws += (size_t)N * 4;
    int*   row_start = (int*)ws;    ws += (size_t)(N + 4) * 4;
    int*   blocksum  = (int*)ws;    ws += 256 * 4;
    int*   blockoff  = (int*)ws;    ws += 256 * 4;
    int2*  epk       = (int2*)ws;   ws += (size_t)E * 8;

    hipMemsetAsync(counts, 0, (size_t)N * 2 * 4, stream);   // counts + cursor adjacent

    convb_kernel<<<16, 256, 0, stream>>>(Wl, WlT);
    film_kernel<<<dim3(B, 2), 256, 0, stream>>>(cond_feats, Wc, bc, gamma, beta);
    node_mfma_kernel<<<(N + TM - 1) / TM, 256, 0, stream>>>(node_feats, WlT, batch_ids,
                                                            gamma, beta, x, N);
    count_kernel<<<(E + 255) / 256, 256, 0, stream>>>(node_i, counts, E);
    int nb = (N + SCAN_ITEMS - 1) / SCAN_ITEMS;
    scan1_kernel<<<nb, 256, 0, stream>>>(counts, row_start, blocksum, N);
    scan2_kernel<<<1, 64, 0, stream>>>(blocksum, blockoff, row_start, nb, N);
    scan3_kernel<<<nb, 256, 0, stream>>>(row_start, blockoff, N);
    fill_kernel<<<(E + 255) / 256, 256, 0, stream>>>(node_j, node_i, edge_w, edge_p,
                                                     row_start, cursor, epk, E);
    agg_kernel<<<(N + 3) / 4, 256, 0, stream>>>(x, epk, row_start, out, N);
}